// Round 4
// baseline (203.868 us; speedup 1.0000x reference)
//
#include <hip/hip_runtime.h>
#include <math.h>

#define NN 8192
#define CC 4096
#define SLOTS 64
#define BLK 256

// out = sum_c cnt_c * value_c * NUM_POS / N^2 ; NUM_POS=4, N=8192
#define SCALE (4.0f / (8192.0f * 8192.0f))

__global__ void init_kernel(int* __restrict__ counts) {
    int i = blockIdx.x * blockDim.x + threadIdx.x;
    if (i < CC) counts[i] = 0;
}

__global__ void build_index(const int* __restrict__ label,
                            int* __restrict__ counts,
                            int* __restrict__ lists) {
    int i = blockIdx.x * blockDim.x + threadIdx.x;
    if (i < NN) {
        int lab = label[i];
        int pos = atomicAdd(&counts[lab], 1);
        if (pos < SLOTS) lists[lab * SLOTS + pos] = i;
    }
}

// One block per class. Wave w owns float4 slots w*256 + i*64 + lane (i<4),
// i.e. a contiguous 1 KB column slice. Row loop processes 4 rows per
// iteration with all 16 loads in flight -> dependent-chain length ceil(m/4)
// instead of m. Tail rows duplicate row 0 (MSHR-merged) with weight 0.
__global__ __launch_bounds__(BLK) void class_loss(const float* __restrict__ feat,
                                                  const int* __restrict__ counts,
                                                  const int* __restrict__ lists,
                                                  float* __restrict__ value) {
    int c = blockIdx.x;
    int t = threadIdx.x;
    int lane = t & 63, w = t >> 6;

    __shared__ int s_cnt;
    __shared__ int s_rows[SLOTS];
    if (t == 0) s_cnt = counts[c];
    if (t < SLOTS) s_rows[t] = lists[c * SLOTS + t];  // junk past cnt unused
    __syncthreads();

    int cnt = s_cnt;
    if (cnt == 0) {
        if (t == 0) value[c] = 0.0f;
        return;
    }
    int m = cnt < SLOTS ? cnt : SLOTS;

    float4 a[4];
    #pragma unroll
    for (int i = 0; i < 4; ++i) a[i] = make_float4(0.f, 0.f, 0.f, 0.f);

    int base_slot = w * 256 + lane;
    int r0 = s_rows[0];

    for (int k = 0; k < m; k += 4) {
        int ra = s_rows[k];
        int rb = (k + 1 < m) ? s_rows[k + 1] : r0;
        int rc = (k + 2 < m) ? s_rows[k + 2] : r0;
        int rd = (k + 3 < m) ? s_rows[k + 3] : r0;
        float fb = (k + 1 < m) ? 1.f : 0.f;
        float fc = (k + 2 < m) ? 1.f : 0.f;
        float fd = (k + 3 < m) ? 1.f : 0.f;
        const float4* pa = (const float4*)(feat + (size_t)ra * CC);
        const float4* pb = (const float4*)(feat + (size_t)rb * CC);
        const float4* pc = (const float4*)(feat + (size_t)rc * CC);
        const float4* pd = (const float4*)(feat + (size_t)rd * CC);

        float4 va[4], vb[4], vc4[4], vd[4];
        #pragma unroll
        for (int i = 0; i < 4; ++i) va[i] = pa[base_slot + i * 64];
        #pragma unroll
        for (int i = 0; i < 4; ++i) vb[i] = pb[base_slot + i * 64];
        #pragma unroll
        for (int i = 0; i < 4; ++i) vc4[i] = pc[base_slot + i * 64];
        #pragma unroll
        for (int i = 0; i < 4; ++i) vd[i] = pd[base_slot + i * 64];

        #pragma unroll
        for (int i = 0; i < 4; ++i) {
            a[i].x += va[i].x + fb * vb[i].x + fc * vc4[i].x + fd * vd[i].x;
            a[i].y += va[i].y + fb * vb[i].y + fc * vc4[i].y + fd * vd[i].y;
            a[i].z += va[i].z + fb * vb[i].z + fc * vc4[i].z + fd * vd[i].z;
            a[i].w += va[i].w + fb * vb[i].w + fc * vc4[i].w + fd * vd[i].w;
        }
    }

    float inv = 1.0f / (float)cnt;
    float vals[16];
    #pragma unroll
    for (int i = 0; i < 4; ++i) {
        vals[i * 4 + 0] = a[i].x * inv;
        vals[i * 4 + 1] = a[i].y * inv;
        vals[i * 4 + 2] = a[i].z * inv;
        vals[i * 4 + 3] = a[i].w * inv;
    }

    __shared__ float s_red[4];
    __shared__ float s_bcast;
    __shared__ float s_vc;

    // --- block max ---
    float wm = vals[0];
    #pragma unroll
    for (int j = 1; j < 16; ++j) wm = fmaxf(wm, vals[j]);
    #pragma unroll
    for (int off = 1; off < 64; off <<= 1) wm = fmaxf(wm, __shfl_xor(wm, off, 64));
    if (lane == 0) s_red[w] = wm;
    __syncthreads();
    if (t == 0) s_bcast = fmaxf(fmaxf(s_red[0], s_red[1]), fmaxf(s_red[2], s_red[3]));
    __syncthreads();
    float M = s_bcast;

    // --- block sum of exp(v - M); owner deposits v at column c ---
    // col c lives in slot s=c>>2 comp j=c&3; s = w*256 + i*64 + l
    int s_idx = c >> 2, cj = c & 3;
    int ow = s_idx >> 8, orem = s_idx & 255;
    int oi = orem >> 6, ol = orem & 63;
    float se = 0.f;
    #pragma unroll
    for (int j = 0; j < 16; ++j) se += __expf(vals[j] - M);
    #pragma unroll
    for (int off = 1; off < 64; off <<= 1) se += __shfl_xor(se, off, 64);
    if (lane == 0) s_red[w] = se;
    if (t == ow * 64 + ol) s_vc = vals[oi * 4 + cj];
    __syncthreads();

    if (t == 0) {
        float S = s_red[0] + s_red[1] + s_red[2] + s_red[3];
        value[c] = (float)cnt * (M + __logf(S) - s_vc);
    }
}

__global__ __launch_bounds__(BLK) void finalize(const float* __restrict__ value,
                                                float* __restrict__ out) {
    int t = threadIdx.x;
    const float4* v4 = (const float4*)value;
    float s = 0.f;
    #pragma unroll
    for (int i = 0; i < CC / 4 / BLK; ++i) {
        float4 v = v4[i * BLK + t];
        s += v.x + v.y + v.z + v.w;
    }
    #pragma unroll
    for (int off = 1; off < 64; off <<= 1) s += __shfl_xor(s, off, 64);
    __shared__ float s_red[4];
    int lane = t & 63, wv = t >> 6;
    if (lane == 0) s_red[wv] = s;
    __syncthreads();
    if (t == 0) out[0] = (s_red[0] + s_red[1] + s_red[2] + s_red[3]) * SCALE;
}

extern "C" void kernel_launch(void* const* d_in, const int* in_sizes, int n_in,
                              void* d_out, int out_size, void* d_ws, size_t ws_size,
                              hipStream_t stream) {
    const float* feat = (const float*)d_in[0];
    const int* label = (const int*)d_in[1];
    float* out = (float*)d_out;

    int* counts = (int*)d_ws;                    // CC ints
    int* lists = counts + CC;                    // CC * SLOTS ints
    float* value = (float*)(lists + CC * SLOTS); // CC floats

    init_kernel<<<(CC + BLK - 1) / BLK, BLK, 0, stream>>>(counts);
    build_index<<<(NN + BLK - 1) / BLK, BLK, 0, stream>>>(label, counts, lists);
    class_loss<<<CC, BLK, 0, stream>>>(feat, counts, lists, value);
    finalize<<<1, BLK, 0, stream>>>(value, out);
}